// Round 10
// baseline (711.394 us; speedup 1.0000x reference)
//
#include <hip/hip_runtime.h>
#include <hip/hip_fp16.h>
#include <hip/hip_cooperative_groups.h>
#include <math.h>

namespace cg = cooperative_groups;

#define NNODES 50000
#define NEDGES 800000
#define NF 128
#define BK 128                   // bucket slots per node (4 shards x 32)
#define NTHR 256
constexpr float LN_EPS = 1e-5f;

typedef short v8s __attribute__((ext_vector_type(8)));
typedef unsigned short v8u __attribute__((ext_vector_type(8)));
typedef float v4f __attribute__((ext_vector_type(4)));

__device__ __forceinline__ float clean0(float v) {
    return (isnan(v) || isinf(v)) ? 0.0f : v;
}
__device__ __forceinline__ float cleanw(float v) {
    if (isnan(v)) return 0.0f;
    if (isinf(v)) return v > 0.0f ? 1.0f : 0.0f;
    return v;
}
__device__ __forceinline__ int clampN(int v) {
    return min(max(v, 0), NNODES - 1);
}
__device__ __forceinline__ int pad8(int v) { return (v + 7) & ~7; }

__device__ __forceinline__ unsigned short f2bf(float f) {
    unsigned int u = __float_as_uint(f);
    return (unsigned short)((u + 0x7FFFu + ((u >> 16) & 1u)) >> 16);
}
__device__ __forceinline__ float bf2f(unsigned short h) {
    return __uint_as_float(((unsigned int)h) << 16);
}
__device__ __forceinline__ void split_bf(float v, unsigned short& h, unsigned short& l) {
    h = f2bf(v);
    l = f2bf(v - bf2f(h));
}

struct Params {
    const int* ei; const float* ea;
    const float* x; const float* g; const float* be;
    const float* W1; const float* b1;
    const float* W2; const float* b2;
    const float* W3; const float* b3;
    float* out;
    unsigned short* zbuf; unsigned short* hbuf;
    float* dis; int* cnt4; int* cntp; int2* bucket; float* h3;
    unsigned short* Wh1T; unsigned short* Wl1T;
    unsigned short* Wh2T; unsigned short* Wl2T;
};

// ---- GEMM phase: C[r,:] = fp16( dis[r] * ((Ah+Al) @ (Wh+Wl)) ) ----------
// split-bf16 3-product; wave owns 16 rows x 128 cols; tile = 64 rows/block.
__device__ __forceinline__ void gemm_phase(
        const unsigned short* __restrict__ Ain,
        const unsigned short* __restrict__ BhT, const unsigned short* __restrict__ BlT,
        const float* __restrict__ dis, unsigned short* __restrict__ C) {
    int w = threadIdx.x >> 6;
    int lane = threadIdx.x & 63;
    int m = lane & 15;
    int q = lane >> 4;
    const int ntiles = (NNODES + 63) / 64;      // 782
    for (int tile = blockIdx.x; tile < ntiles; tile += gridDim.x) {
        int rowbase = tile * 64 + w * 16;
        int arow = min(rowbase + m, NNODES - 1);

        const v8u* ap = (const v8u*)(Ain + (size_t)arow * NF);
        v8s afh[4], afl[4];
        #pragma unroll
        for (int c = 0; c < 4; c++) {
            v8u a = ap[c * 4 + q];
            #pragma unroll
            for (int j = 0; j < 8; j++) {
                float f = __half2float(__ushort_as_half(a[j]));
                unsigned short hh, ll;
                split_bf(f, hh, ll);
                afh[c][j] = (short)hh;
                afl[c][j] = (short)ll;
            }
        }
        float ds[4];
        #pragma unroll
        for (int r = 0; r < 4; r++) ds[r] = dis[min(rowbase + q * 4 + r, NNODES - 1)];

        for (int nt = 0; nt < 8; nt++) {
            int n0 = nt * 16;
            const v8s* bhp = (const v8s*)(BhT + (size_t)(n0 + m) * NF);
            const v8s* blp = (const v8s*)(BlT + (size_t)(n0 + m) * NF);
            v4f acc = {0.f, 0.f, 0.f, 0.f};
            #pragma unroll
            for (int c = 0; c < 4; c++) {
                v8s bh = bhp[c * 4 + q];
                v8s bl = blp[c * 4 + q];
                acc = __builtin_amdgcn_mfma_f32_16x16x32_bf16(afh[c], bh, acc, 0, 0, 0);
                acc = __builtin_amdgcn_mfma_f32_16x16x32_bf16(afh[c], bl, acc, 0, 0, 0);
                acc = __builtin_amdgcn_mfma_f32_16x16x32_bf16(afl[c], bh, acc, 0, 0, 0);
            }
            #pragma unroll
            for (int r = 0; r < 4; r++) {
                int gr = rowbase + q * 4 + r;
                if (gr < NNODES)
                    C[(size_t)gr * NF + n0 + m] = __half_as_ushort(__float2half(acc[r] * ds[r]));
            }
        }
    }
}

// ---- aggregation phase: wave/node grid-stride, fp16 gathers -------------
// LAST=false: y = fp16(relu(dis_n*acc + b)).  LAST=true: h3[n]=dis_n*dot(.,W3)
template <bool LAST>
__device__ __forceinline__ void agg_phase(
        const unsigned short* __restrict__ h, const float* __restrict__ dis,
        const int* __restrict__ cntp, const int2* __restrict__ bucket,
        const float* __restrict__ bias, unsigned short* __restrict__ y,
        const float* __restrict__ W3, float* __restrict__ h3) {
    int lane = threadIdx.x & 63;
    int wave0 = (blockIdx.x * NTHR + threadIdx.x) >> 6;
    int nwaves = gridDim.x << 2;
    const __half2* hp = (const __half2*)h;
    for (int nn = wave0; nn < NNODES; nn += nwaves) {
        int n = __builtin_amdgcn_readfirstlane(nn);
        float2 acc = __half22float2(hp[(size_t)n * 64 + lane]);   // self term
        int beg = n << 7;
        int end = beg + cntp[n];
        int p = beg;
        if (p < end) {
            int2 rec[8];
            #pragma unroll
            for (int j = 0; j < 8; j++) rec[j] = bucket[p + j];
            p += 8;
            while (p < end) {
                float2 v[8];
                #pragma unroll
                for (int j = 0; j < 8; j++) v[j] = __half22float2(hp[(size_t)rec[j].x * 64 + lane]);
                int2 rec2[8];
                #pragma unroll
                for (int j = 0; j < 8; j++) rec2[j] = bucket[p + j];
                #pragma unroll
                for (int j = 0; j < 8; j++) {
                    float w = __int_as_float(rec[j].y);
                    acc.x += v[j].x * w;
                    acc.y += v[j].y * w;
                }
                #pragma unroll
                for (int j = 0; j < 8; j++) rec[j] = rec2[j];
                p += 8;
            }
            float2 v[8];
            #pragma unroll
            for (int j = 0; j < 8; j++) v[j] = __half22float2(hp[(size_t)rec[j].x * 64 + lane]);
            #pragma unroll
            for (int j = 0; j < 8; j++) {
                float w = __int_as_float(rec[j].y);
                acc.x += v[j].x * w;
                acc.y += v[j].y * w;
            }
        }
        float dn = dis[n];
        float2 b = ((const float2*)bias)[lane];
        float ox = fmaxf(acc.x * dn + b.x, 0.0f);
        float oy = fmaxf(acc.y * dn + b.y, 0.0f);
        if (LAST) {
            float2 w3 = ((const float2*)W3)[lane];
            float s = ox * w3.x + oy * w3.y;
            for (int o = 32; o > 0; o >>= 1) s += __shfl_xor(s, o);
            if (lane == 0) h3[n] = s * dn;
        } else {
            ((__half2*)y)[(size_t)n * 64 + lane] = __float22half2_rn(make_float2(ox, oy));
        }
    }
}

// ---- the whole model in one cooperative kernel --------------------------
__global__ __launch_bounds__(256, 4) void k_mega(Params P) {
    cg::grid_group grid = cg::this_grid();
    const int tid = blockIdx.x * NTHR + threadIdx.x;
    const int nthreads = gridDim.x * NTHR;
    const int lane = threadIdx.x & 63;
    const int wave0 = tid >> 6;
    const int nwaves = gridDim.x << 2;

    // phase 1a: sharded bucket build (1 atomic + 1 random 8B store / edge)
    for (int e = tid; e < NEDGES; e += nthreads) {
        int r = clampN(P.ei[e]);
        int c = clampN(P.ei[NEDGES + e]);
        float w = cleanw(P.ea[e]);
        int s = e & 3;
        int pos = atomicAdd(&P.cnt4[(c << 2) + s], 1);
        if (pos < 32) P.bucket[(c << 7) + (s << 5) + pos] = make_int2(r, __float_as_int(w));
    }
    // phase 1b: LayerNorm (wave per node) -> zbuf fp16
    for (int n = wave0; n < NNODES; n += nwaves) {
        float2 v = ((const float2*)(P.x + (size_t)n * NF))[lane];
        v.x = clean0(v.x); v.y = clean0(v.y);
        float s = v.x + v.y;
        for (int o = 32; o > 0; o >>= 1) s += __shfl_xor(s, o);
        float mu = s * (1.0f / NF);
        float dx = v.x - mu, dy = v.y - mu;
        float q = dx * dx + dy * dy;
        for (int o = 32; o > 0; o >>= 1) q += __shfl_xor(q, o);
        float rstd = rsqrtf(q * (1.0f / NF) + LN_EPS);
        float2 g = ((const float2*)P.g)[lane];
        float2 b = ((const float2*)P.be)[lane];
        float ox = dx * rstd * g.x + b.x;
        float oy = dy * rstd * g.y + b.y;
        ((__half2*)P.zbuf)[(size_t)n * 64 + lane] = __float22half2_rn(make_float2(ox, oy));
    }
    grid.sync();

    // phase 2a: shard compaction + deg/dis + pad fill + padded count
    for (int n = tid; n < NNODES; n += nthreads) {
        int4 c4 = ((const int4*)P.cnt4)[n];
        int cs[4] = { min(c4.x, 32), min(c4.y, 32), min(c4.z, 32), min(c4.w, 32) };
        int base = n << 7;
        float d = 1.0f;
        for (int i = 0; i < cs[0]; i++) d += __int_as_float(P.bucket[base + i].y);
        int total = cs[0];
        #pragma unroll
        for (int s = 1; s < 4; s++) {
            int src = base + (s << 5);
            for (int i = 0; i < cs[s]; i++) {
                int2 rec = P.bucket[src + i];
                d += __int_as_float(rec.y);
                P.bucket[base + total + i] = rec;
            }
            total += cs[s];
        }
        for (int p = total; p < pad8(total); p++) P.bucket[base + p] = make_int2(0, 0);
        P.dis[n] = rsqrtf(d);                  // d >= 1 always
        P.cntp[n] = pad8(total);
    }
    // phase 2b: W1/W2 split into bf16 hi/lo transposed [n][k]
    for (int idx = tid; idx < 32768; idx += nthreads) {
        int m = idx >> 14;
        int n = (idx >> 7) & 127;
        int k = idx & 127;
        const float* W = m ? P.W2 : P.W1;
        unsigned short* Wh = m ? P.Wh2T : P.Wh1T;
        unsigned short* Wl = m ? P.Wl2T : P.Wl1T;
        unsigned short h, l;
        split_bf(W[k * 128 + n], h, l);
        Wh[n * 128 + k] = h;
        Wl[n * 128 + k] = l;
    }
    grid.sync();

    // phase 3: gemm1  zbuf -> hbuf
    gemm_phase(P.zbuf, P.Wh1T, P.Wl1T, P.dis, P.hbuf);
    grid.sync();
    // phase 4: agg1  hbuf -> zbuf
    agg_phase<false>(P.hbuf, P.dis, P.cntp, P.bucket, P.b1, P.zbuf, nullptr, nullptr);
    grid.sync();
    // phase 5: gemm2  zbuf -> hbuf
    gemm_phase(P.zbuf, P.Wh2T, P.Wl2T, P.dis, P.hbuf);
    grid.sync();
    // phase 6: agg2 + fused output GEMV  hbuf -> h3
    agg_phase<true>(P.hbuf, P.dis, P.cntp, P.bucket, P.b2, nullptr, P.W3, P.h3);
    grid.sync();
    // phase 7: output scalar aggregation  h3 -> out
    for (int n = tid; n < NNODES; n += nthreads) {
        float acc = P.h3[n];
        int beg = n << 7;
        int end = beg + P.cntp[n];
        for (int p = beg; p + 4 <= end; p += 4) {
            int2 e0 = P.bucket[p], e1 = P.bucket[p + 1];
            int2 e2 = P.bucket[p + 2], e3 = P.bucket[p + 3];
            float v0 = P.h3[e0.x], v1 = P.h3[e1.x], v2 = P.h3[e2.x], v3 = P.h3[e3.x];
            acc += v0 * __int_as_float(e0.y) + v1 * __int_as_float(e1.y)
                 + v2 * __int_as_float(e2.y) + v3 * __int_as_float(e3.y);
        }
        P.out[n] = acc * P.dis[n] + P.b3[0];
    }
}

extern "C" void kernel_launch(void* const* d_in, const int* in_sizes, int n_in,
                              void* d_out, int out_size, void* d_ws, size_t ws_size,
                              hipStream_t stream) {
    char* ws = (char*)d_ws;
    size_t off = 0;
    auto alloc = [&](size_t bytes) {
        void* p = ws + off;
        off += (bytes + 255) & ~((size_t)255);
        return p;
    };
    Params P;
    P.ei = (const int*)d_in[1];
    P.ea = (const float*)d_in[2];
    P.x  = (const float*)d_in[0];
    P.g  = (const float*)d_in[3];
    P.be = (const float*)d_in[4];
    P.W1 = (const float*)d_in[5];  P.b1 = (const float*)d_in[6];
    P.W2 = (const float*)d_in[7];  P.b2 = (const float*)d_in[8];
    P.W3 = (const float*)d_in[9];  P.b3 = (const float*)d_in[10];
    P.out = (float*)d_out;
    P.zbuf = (unsigned short*)alloc((size_t)NNODES * NF * 2);
    P.hbuf = (unsigned short*)alloc((size_t)NNODES * NF * 2);
    P.dis  = (float*)alloc((size_t)NNODES * 4);
    P.cnt4 = (int*)  alloc((size_t)NNODES * 16);
    P.cntp = (int*)  alloc((size_t)NNODES * 4);
    P.bucket = (int2*)alloc((size_t)NNODES * BK * 8);
    P.h3   = (float*)alloc((size_t)NNODES * 4);
    P.Wh1T = (unsigned short*)alloc(128 * 128 * 2);
    P.Wl1T = (unsigned short*)alloc(128 * 128 * 2);
    P.Wh2T = (unsigned short*)alloc(128 * 128 * 2);
    P.Wl2T = (unsigned short*)alloc(128 * 128 * 2);
    (void)ws_size; (void)in_sizes; (void)n_in; (void)out_size;

    hipMemsetAsync(P.cnt4, 0, (size_t)NNODES * 16, stream);

    // grid: 1024 blocks if co-residency allows (launch_bounds(256,4) => 4 blk/CU)
    int perCU = 4;
    hipOccupancyMaxActiveBlocksPerMultiprocessor(&perCU, k_mega, NTHR, 0);
    int grid = min(1024, perCU * 256);
    void* args[] = { &P };
    hipLaunchCooperativeKernel((void*)k_mega, dim3(grid), dim3(NTHR), args, 0, stream);
}

// Round 11
// 290.573 us; speedup vs baseline: 2.4482x; 2.4482x over previous
//
#include <hip/hip_runtime.h>
#include <hip/hip_fp16.h>
#include <math.h>

#define NNODES 50000
#define NEDGES 800000
#define NF 128
#define BK 64                    // bucket slots per node (P(deg>=64) ~ 1e-18)
constexpr float LN_EPS = 1e-5f;

typedef short v8s __attribute__((ext_vector_type(8)));
typedef unsigned short v8u __attribute__((ext_vector_type(8)));
typedef float v4f __attribute__((ext_vector_type(4)));

__device__ __forceinline__ float clean0(float v) {
    return (isnan(v) || isinf(v)) ? 0.0f : v;
}
__device__ __forceinline__ float cleanw(float v) {
    if (isnan(v)) return 0.0f;
    if (isinf(v)) return v > 0.0f ? 1.0f : 0.0f;
    return v;
}
__device__ __forceinline__ int clampN(int v) {
    return min(max(v, 0), NNODES - 1);
}
__device__ __forceinline__ int pad8(int v) { return (v + 7) & ~7; }

// bf16 helpers (RNE)
__device__ __forceinline__ unsigned short f2bf(float f) {
    unsigned int u = __float_as_uint(f);
    return (unsigned short)((u + 0x7FFFu + ((u >> 16) & 1u)) >> 16);
}
__device__ __forceinline__ float bf2f(unsigned short h) {
    return __uint_as_float(((unsigned int)h) << 16);
}
__device__ __forceinline__ void split_bf(float v, unsigned short& h, unsigned short& l) {
    h = f2bf(v);
    l = f2bf(v - bf2f(h));
}

// ---- kernel A: bucket build (blocks < nbb) UNION layernorm --------------
// build: 1 atomic + 1 random 8B store per edge (op-throughput bound).
// layernorm: independent of the graph; fills build's latency-bound tail.
__global__ void k_build_ln(const int* __restrict__ ei, const float* __restrict__ ea,
                           int* __restrict__ cnt, int2* __restrict__ bucket,
                           const float* __restrict__ x, const float* __restrict__ gamma,
                           const float* __restrict__ beta, unsigned short* __restrict__ z,
                           int nbb) {
    if ((int)blockIdx.x < nbb) {
        int e = blockIdx.x * 256 + threadIdx.x;
        if (e >= NEDGES) return;
        int r = clampN(ei[e]);
        int c = clampN(ei[NEDGES + e]);
        float w = cleanw(ea[e]);
        int pos = atomicAdd(&cnt[c], 1);
        if (pos < BK) bucket[(c << 6) + pos] = make_int2(r, __float_as_int(w));
    } else {
        int bid = blockIdx.x - nbb;
        int n = (bid * 256 + threadIdx.x) >> 6;
        int lane = threadIdx.x & 63;
        if (n >= NNODES) return;
        float2 v = ((const float2*)(x + (size_t)n * NF))[lane];
        v.x = clean0(v.x); v.y = clean0(v.y);
        float s = v.x + v.y;
        for (int o = 32; o > 0; o >>= 1) s += __shfl_xor(s, o);
        float mu = s * (1.0f / NF);
        float dx = v.x - mu, dy = v.y - mu;
        float q = dx * dx + dy * dy;
        for (int o = 32; o > 0; o >>= 1) q += __shfl_xor(q, o);
        float rstd = rsqrtf(q * (1.0f / NF) + LN_EPS);
        float2 g = ((const float2*)gamma)[lane];
        float2 b = ((const float2*)beta)[lane];
        float ox = dx * rstd * g.x + b.x;
        float oy = dy * rstd * g.y + b.y;
        ((__half2*)z)[(size_t)n * 64 + lane] = __float22half2_rn(make_float2(ox, oy));
    }
}

// ---- kernel B: prep. blocks < nbn: deg/dis + pad fill + padded count.
// blocks >= nbn: W1/W2 bf16 hi/lo split, transposed [n][k].
__global__ void k_prep(int2* __restrict__ bucket, int* __restrict__ cnt,
                       float* __restrict__ dis,
                       const float* __restrict__ W1, const float* __restrict__ W2,
                       unsigned short* __restrict__ Wh1T, unsigned short* __restrict__ Wl1T,
                       unsigned short* __restrict__ Wh2T, unsigned short* __restrict__ Wl2T,
                       int nbn) {
    if ((int)blockIdx.x < nbn) {
        int n = blockIdx.x * 256 + threadIdx.x;
        if (n >= NNODES) return;
        int c = min(cnt[n], BK);
        int beg = n << 6;
        float d = 1.0f;
        for (int p = beg; p < beg + c; p++) d += __int_as_float(bucket[p].y);
        for (int p = beg + c; p < beg + pad8(c); p++) bucket[p] = make_int2(0, 0);
        dis[n] = rsqrtf(d);                    // d >= 1 always (self loop)
        cnt[n] = pad8(c);                      // aggregate reads padded length
    } else {
        int idx = (blockIdx.x - nbn) * 256 + threadIdx.x;   // [0, 32768)
        int m = idx >> 14;                                  // which matrix
        int n = (idx >> 7) & 127;
        int k = idx & 127;
        const float* W = m ? W2 : W1;
        unsigned short* Wh = m ? Wh2T : Wh1T;
        unsigned short* Wl = m ? Wl2T : Wl1T;
        unsigned short h, l;
        split_bf(W[k * 128 + n], h, l);
        Wh[n * 128 + k] = h;
        Wl[n * 128 + k] = l;
    }
}

// ---- MFMA GEMM: C[r,:] = fp16( dis[r] * ((Ah+Al) @ (Wh+Wl)) ) -----------
// A input fp16; prologue splits exactly into bf16 hi+lo (fp16 = hi + lo).
__global__ __launch_bounds__(256) void k_gemm_mfma(
        const unsigned short* __restrict__ Ain,
        const unsigned short* __restrict__ BhT, const unsigned short* __restrict__ BlT,
        const float* __restrict__ dis, unsigned short* __restrict__ C) {
    int w = threadIdx.x >> 6;
    int lane = threadIdx.x & 63;
    int m = lane & 15;           // A row within tile / B,C col within tile
    int q = lane >> 4;           // quad
    int rowbase = blockIdx.x * 64 + w * 16;
    int arow = min(rowbase + m, NNODES - 1);

    const v8u* ap = (const v8u*)(Ain + (size_t)arow * NF);
    v8s afh[4], afl[4];
    #pragma unroll
    for (int c = 0; c < 4; c++) {
        v8u a = ap[c * 4 + q];
        #pragma unroll
        for (int j = 0; j < 8; j++) {
            float f = __half2float(__ushort_as_half(a[j]));
            unsigned short hh, ll;
            split_bf(f, hh, ll);
            afh[c][j] = (short)hh;
            afl[c][j] = (short)ll;
        }
    }

    float ds[4];
    #pragma unroll
    for (int r = 0; r < 4; r++) ds[r] = dis[min(rowbase + q * 4 + r, NNODES - 1)];

    for (int nt = 0; nt < 8; nt++) {
        int n0 = nt * 16;
        const v8s* bhp = (const v8s*)(BhT + (size_t)(n0 + m) * NF);
        const v8s* blp = (const v8s*)(BlT + (size_t)(n0 + m) * NF);
        v4f acc = {0.f, 0.f, 0.f, 0.f};
        #pragma unroll
        for (int c = 0; c < 4; c++) {
            v8s bh = bhp[c * 4 + q];
            v8s bl = blp[c * 4 + q];
            acc = __builtin_amdgcn_mfma_f32_16x16x32_bf16(afh[c], bh, acc, 0, 0, 0);
            acc = __builtin_amdgcn_mfma_f32_16x16x32_bf16(afh[c], bl, acc, 0, 0, 0);
            acc = __builtin_amdgcn_mfma_f32_16x16x32_bf16(afl[c], bh, acc, 0, 0, 0);
        }
        #pragma unroll
        for (int r = 0; r < 4; r++) {
            int gr = rowbase + q * 4 + r;
            if (gr < NNODES)
                C[(size_t)gr * NF + n0 + m] = __half_as_ushort(__float2half(acc[r] * ds[r]));
        }
    }
}

// ---- bucket aggregation: wave/node, fp16 gathers (256B/row) -------------
// h pre-scaled by dis[src]. LAST=false: y = fp16(relu(dis_n*acc + b)).
// LAST=true: fused output GEMV — h3[n] = dis_n * dot(relu(...), W3).
template <bool LAST>
__global__ __launch_bounds__(256) void k_aggregate(
        const unsigned short* __restrict__ h, const float* __restrict__ dis,
        const int* __restrict__ cntp, const int2* __restrict__ bucket,
        const float* __restrict__ bias, unsigned short* __restrict__ y,
        const float* __restrict__ W3, float* __restrict__ h3) {
    int n0 = (blockIdx.x * blockDim.x + threadIdx.x) >> 6;
    if (n0 >= NNODES) return;
    int n = __builtin_amdgcn_readfirstlane(n0);
    int lane = threadIdx.x & 63;
    const __half2* hp = (const __half2*)h;             // row stride 64 half2
    float2 acc = __half22float2(hp[(size_t)n * 64 + lane]);   // self term
    int beg = n << 6;
    int end = beg + cntp[n];                           // padded, mult of 8
    int p = beg;
    if (p < end) {
        int2 rec[8];
        #pragma unroll
        for (int j = 0; j < 8; j++) rec[j] = bucket[p + j];
        p += 8;
        while (p < end) {
            float2 v[8];
            #pragma unroll
            for (int j = 0; j < 8; j++) v[j] = __half22float2(hp[(size_t)rec[j].x * 64 + lane]);
            int2 rec2[8];
            #pragma unroll
            for (int j = 0; j < 8; j++) rec2[j] = bucket[p + j];
            #pragma unroll
            for (int j = 0; j < 8; j++) {
                float w = __int_as_float(rec[j].y);
                acc.x += v[j].x * w;
                acc.y += v[j].y * w;
            }
            #pragma unroll
            for (int j = 0; j < 8; j++) rec[j] = rec2[j];
            p += 8;
        }
        float2 v[8];
        #pragma unroll
        for (int j = 0; j < 8; j++) v[j] = __half22float2(hp[(size_t)rec[j].x * 64 + lane]);
        #pragma unroll
        for (int j = 0; j < 8; j++) {
            float w = __int_as_float(rec[j].y);
            acc.x += v[j].x * w;
            acc.y += v[j].y * w;
        }
    }
    float dn = dis[n];
    float2 b = ((const float2*)bias)[lane];
    float ox = fmaxf(acc.x * dn + b.x, 0.0f);
    float oy = fmaxf(acc.y * dn + b.y, 0.0f);
    if (LAST) {
        float2 w3 = ((const float2*)W3)[lane];
        float s = ox * w3.x + oy * w3.y;
        for (int o = 32; o > 0; o >>= 1) s += __shfl_xor(s, o);
        if (lane == 0) h3[n] = s * dn;
    } else {
        ((__half2*)y)[(size_t)n * 64 + lane] = __float22half2_rn(make_float2(ox, oy));
    }
}

// ---- scalar aggregation for output layer (padded buckets) ---------------
__global__ void k_agg_scalar(const float* __restrict__ h3, const float* __restrict__ dis,
                             const int* __restrict__ cntp, const int2* __restrict__ bucket,
                             const float* __restrict__ b3, float* __restrict__ out) {
    int n = blockIdx.x * blockDim.x + threadIdx.x;
    if (n >= NNODES) return;
    float acc = h3[n];
    int beg = n << 6;
    int end = beg + cntp[n];
    for (int p = beg; p + 4 <= end; p += 4) {
        int2 e0 = bucket[p], e1 = bucket[p + 1], e2 = bucket[p + 2], e3 = bucket[p + 3];
        float v0 = h3[e0.x], v1 = h3[e1.x], v2 = h3[e2.x], v3 = h3[e3.x];
        acc += v0 * __int_as_float(e0.y) + v1 * __int_as_float(e1.y)
             + v2 * __int_as_float(e2.y) + v3 * __int_as_float(e3.y);
    }
    out[n] = acc * dis[n] + b3[0];
}

extern "C" void kernel_launch(void* const* d_in, const int* in_sizes, int n_in,
                              void* d_out, int out_size, void* d_ws, size_t ws_size,
                              hipStream_t stream) {
    const float* x  = (const float*)d_in[0];
    const int*   ei = (const int*)d_in[1];
    const float* ea = (const float*)d_in[2];
    const float* g  = (const float*)d_in[3];
    const float* be = (const float*)d_in[4];
    const float* W1 = (const float*)d_in[5];
    const float* b1 = (const float*)d_in[6];
    const float* W2 = (const float*)d_in[7];
    const float* b2 = (const float*)d_in[8];
    const float* W3 = (const float*)d_in[9];
    const float* b3 = (const float*)d_in[10];
    float* out = (float*)d_out;

    char* ws = (char*)d_ws;
    size_t off = 0;
    auto alloc = [&](size_t bytes) {
        void* p = ws + off;
        off += (bytes + 255) & ~((size_t)255);
        return p;
    };
    unsigned short* zbuf = (unsigned short*)alloc((size_t)NNODES * NF * 2);
    unsigned short* hbuf = (unsigned short*)alloc((size_t)NNODES * NF * 2);
    float* dis    = (float*)alloc((size_t)NNODES * 4);
    int*   cnt    = (int*)  alloc((size_t)NNODES * 4);
    int2*  bucket = (int2*) alloc((size_t)NNODES * BK * 8);
    float* h3     = (float*)alloc((size_t)NNODES * 4);
    unsigned short* Wh1T = (unsigned short*)alloc(128 * 128 * 2);
    unsigned short* Wl1T = (unsigned short*)alloc(128 * 128 * 2);
    unsigned short* Wh2T = (unsigned short*)alloc(128 * 128 * 2);
    unsigned short* Wl2T = (unsigned short*)alloc(128 * 128 * 2);
    (void)ws_size; (void)in_sizes; (void)n_in; (void)out_size;

    const int NB_N = (NNODES + 255) / 256;      // 196
    const int NB_E = (NEDGES + 255) / 256;      // 3125
    const int NB_W = (NNODES * 64 + 255) / 256; // 12500 (wave per node)
    const int NB_G = (NNODES + 63) / 64;        // 782  (gemm 64-row tiles)

    hipMemsetAsync(cnt, 0, (size_t)NNODES * 4, stream);
    // A: bucket build UNION layernorm (independent work overlapped)
    k_build_ln<<<NB_E + NB_W, 256, 0, stream>>>(ei, ea, cnt, bucket,
                                                x, g, be, zbuf, NB_E);
    // B: deg/dis + pads + weight split
    k_prep<<<NB_N + 128, 256, 0, stream>>>(bucket, cnt, dis,
                                           W1, W2, Wh1T, Wl1T, Wh2T, Wl2T, NB_N);

    // layer 1
    k_gemm_mfma<<<NB_G, 256, 0, stream>>>(zbuf, Wh1T, Wl1T, dis, hbuf);
    k_aggregate<false><<<NB_W, 256, 0, stream>>>(hbuf, dis, cnt, bucket, b1, zbuf,
                                                 nullptr, nullptr);
    // layer 2
    k_gemm_mfma<<<NB_G, 256, 0, stream>>>(zbuf, Wh2T, Wl2T, dis, hbuf);
    // layer 2 aggregate with fused output GEMV -> h3
    k_aggregate<true><<<NB_W, 256, 0, stream>>>(hbuf, dis, cnt, bucket, b2, nullptr,
                                                W3, h3);
    // output layer scalar aggregation
    k_agg_scalar<<<NB_N, 256, 0, stream>>>(h3, dis, cnt, bucket, b3, out);
}